// Round 1
// baseline (59.150 us; speedup 1.0000x reference)
//
#include <hip/hip_runtime.h>

// YOLOv1 loss, forward only. Inputs: preds (N,7,7,30) f32, targets (N,7,7,30) f32.
// Output: scalar f32. Per-cell contribution:
//   coo  = (T4 > 0), noo = (T4 == 0)
//   noobj   = noo * ((P4-T4)^2 + (P9-T9)^2)
//   iou_b   = IoU(pred box b, pred box 0)   (note: reference compares vs PRED box0)
//   idx     = argmax(iou)  [np semantics: first max; NaN acts as max]
//   contain = coo * (P[5*idx+4] - max_iou)^2
//   ncl     = coo * P[5*(1-idx)+4]^2
//   loss   += contain + 0.5*ncl + 0.5*noobj      (loc_loss and class_loss are exactly 0)
// total = sum / 16384

__global__ __launch_bounds__(256) void yolo_loss_kernel(
    const float* __restrict__ preds,
    const float* __restrict__ targets,
    float* __restrict__ out,
    int ncells)
{
    int cell = blockIdx.x * 256 + threadIdx.x;
    float contrib = 0.0f;
    if (cell < ncells) {
        long base = (long)cell * 30;

        // preds channels 0..9 (cell base is 8B-aligned: 120 % 16 == 8, so float2)
        float p[10];
        #pragma unroll
        for (int k = 0; k < 5; ++k) {
            float2 v = *reinterpret_cast<const float2*>(preds + base + 2 * k);
            p[2 * k] = v.x;
            p[2 * k + 1] = v.y;
        }
        float t4 = targets[base + 4];
        float t9 = targets[base + 9];

        float coo = (t4 > 0.0f) ? 1.0f : 0.0f;
        float noo = (t4 == 0.0f) ? 1.0f : 0.0f;

        float d4 = p[4] - t4;
        float d9 = p[9] - t9;
        float noo_term = noo * (d4 * d4 + d9 * d9);

        // target box for IoU = pred box 0 (reference quirk)
        float lt2x = p[0] / 14.0f - 0.5f * p[2];
        float lt2y = p[1] / 14.0f - 0.5f * p[3];
        float rb2x = p[0] / 14.0f + 0.5f * p[2];
        float rb2y = p[1] / 14.0f + 0.5f * p[3];
        float area2 = (rb2x - lt2x) * (rb2y - lt2y);

        float iou[2];
        #pragma unroll
        for (int b = 0; b < 2; ++b) {
            float x = p[5 * b] / 14.0f;
            float y = p[5 * b + 1] / 14.0f;
            float w = p[5 * b + 2];
            float h = p[5 * b + 3];
            float lt1x = x - 0.5f * w, lt1y = y - 0.5f * h;
            float rb1x = x + 0.5f * w, rb1y = y + 0.5f * h;
            float iltx = fmaxf(lt1x, lt2x), ilty = fmaxf(lt1y, lt2y);
            float irbx = fminf(rb1x, rb2x), irby = fminf(rb1y, rb2y);
            float iwx = fmaxf(irbx - iltx, 0.0f);
            float iwy = fmaxf(irby - ilty, 0.0f);
            float inter = iwx * iwy;
            float area1 = (rb1x - lt1x) * (rb1y - lt1y);
            iou[b] = inter / (area1 + area2 - inter);
        }

        // np.argmax semantics: first occurrence of max; NaN compares as maximum.
        int idx;
        float max_iou;
        if (isnan(iou[0]))      { idx = 0; max_iou = iou[0]; }
        else if (isnan(iou[1])) { idx = 1; max_iou = iou[1]; }
        else                    { idx = (iou[1] > iou[0]) ? 1 : 0;
                                  max_iou = fmaxf(iou[0], iou[1]); }

        float resp4  = p[5 * idx + 4];
        float nresp4 = p[5 * (1 - idx) + 4];
        float cdiff  = resp4 - max_iou;
        float contain = cdiff * cdiff;
        float ncl     = nresp4 * nresp4;

        contrib = coo * (contain + 0.5f * ncl) + 0.5f * noo_term;
    }

    // wave (64-lane) shuffle reduce
    #pragma unroll
    for (int off = 32; off > 0; off >>= 1)
        contrib += __shfl_down(contrib, off, 64);

    __shared__ float warp_sums[4];
    int lane = threadIdx.x & 63;
    int wid  = threadIdx.x >> 6;
    if (lane == 0) warp_sums[wid] = contrib;
    __syncthreads();

    if (threadIdx.x == 0) {
        float s = warp_sums[0] + warp_sums[1] + warp_sums[2] + warp_sums[3];
        atomicAdd(out, s * (1.0f / 16384.0f));
    }
}

extern "C" void kernel_launch(void* const* d_in, const int* in_sizes, int n_in,
                              void* d_out, int out_size, void* d_ws, size_t ws_size,
                              hipStream_t stream) {
    const float* preds   = (const float*)d_in[0];
    const float* targets = (const float*)d_in[1];
    float* out = (float*)d_out;

    int ncells = in_sizes[0] / 30;  // 16384*7*7 = 802816

    hipMemsetAsync(d_out, 0, sizeof(float), stream);

    int block = 256;
    int grid = (ncells + block - 1) / block;  // 3136
    yolo_loss_kernel<<<grid, block, 0, stream>>>(preds, targets, out, ncells);
}